// Round 1
// baseline (164.765 us; speedup 1.0000x reference)
//
#include <hip/hip_runtime.h>

typedef __bf16 bf16;
typedef __bf16 bf16x8 __attribute__((ext_vector_type(8)));
typedef float f32x4 __attribute__((ext_vector_type(4)));

#define S_LEN 2048
#define EMBD 2048
#define HD 128
#define NBATCH 8

// frag->column map: pairs (2f,2f+1) are RoPE pairs (col, col+64) when col<256.
// cols 0-127 = Q, 128-255 = K, 256-383 = V.
__device__ __constant__ int c_nmap[4][6] = {
    {0, 64, 16, 80, 32, 96},
    {48, 112, 128, 192, 144, 208},
    {160, 224, 176, 240, 256, 272},
    {288, 304, 320, 336, 352, 368},
};

__device__ inline void gload16(const void* g, void* l) {
  __builtin_amdgcn_global_load_lds(
      (const __attribute__((address_space(1))) unsigned int*)g,
      (__attribute__((address_space(3))) unsigned int*)l, 16, 0, 0);
}

// ---------------------------------------------------------------------------
// K0: Wt[mat][n][k] = bf16( W[ (k&~63) | ((k&63) ^ ((n&7)<<3)) ][n] )
// (transpose + bf16 + bake the LDS XOR-swizzle into global layout)
// ---------------------------------------------------------------------------
__global__ void k_prep(const float* __restrict__ Wq, const float* __restrict__ Wk,
                       const float* __restrict__ Wv, bf16* __restrict__ wt) {
  int idx = blockIdx.x * blockDim.x + threadIdx.x;  // 3*128*2048 threads exact
  int k = idx & 2047;
  int n = (idx >> 11) & 127;
  int mat = idx >> 18;
  int ksrc = (k & ~63) | ((k & 63) ^ ((n & 7) << 3));
  const float* W = (mat == 0) ? Wq : ((mat == 1) ? Wk : Wv);
  wt[idx] = (bf16)W[(size_t)ksrc * HD + n];
}

// ---------------------------------------------------------------------------
// K1: fused QKV GEMM + bias + RoPE. BM=64, BN=384, BK=64, 8 waves (2m x 4n).
// Writes Qw[b][s][128] (plain), Kw[b][s][128] (col-swizzled by s&7),
// Vtw[b][dv][2048] (transposed, token-slot swizzled by dv&7).
// ---------------------------------------------------------------------------
__global__ __launch_bounds__(512) void k_qkv(
    const float* __restrict__ x, const bf16* __restrict__ wt,
    const float* __restrict__ bq, const float* __restrict__ bk,
    const float* __restrict__ bv, bf16* __restrict__ Qw, bf16* __restrict__ Kw,
    bf16* __restrict__ Vtw) {
  __shared__ __align__(16) bf16 xs[64 * 72];     // padded rows: conflict-free
  __shared__ __align__(16) bf16 wts[384 * 64];   // linear, swizzle pre-baked

  const int tid = threadIdx.x;
  const int lane = tid & 63;
  const int wave = tid >> 6;
  const int wm = wave >> 2;   // 0..1
  const int wn = wave & 3;    // 0..3
  const int l15 = lane & 15;
  const int lh = lane >> 4;   // 0..3
  const int row0 = blockIdx.x * 64;

  int nm[6];
#pragma unroll
  for (int f = 0; f < 6; ++f) nm[f] = c_nmap[wn][f];

  f32x4 acc[2][6];
#pragma unroll
  for (int mf = 0; mf < 2; ++mf)
#pragma unroll
    for (int f = 0; f < 6; ++f) acc[mf][f] = {};

  for (int ks = 0; ks < EMBD / 64; ++ks) {
    __syncthreads();
    // stage x tile 64x64 (f32 -> bf16), padded stride 72
#pragma unroll
    for (int i = 0; i < 2; ++i) {
      int e = (i * 512 + tid) * 4;
      int r = e >> 6, k = e & 63;
      const float4 v = *(const float4*)(x + (size_t)(row0 + r) * EMBD + ks * 64 + k);
      union { bf16 h[4]; uint2 u; } p;
      p.h[0] = (bf16)v.x; p.h[1] = (bf16)v.y; p.h[2] = (bf16)v.z; p.h[3] = (bf16)v.w;
      *(uint2*)&xs[r * 72 + k] = p.u;
    }
    // stage Wt tile 384x64 via global_load_lds (linear copy; swizzle pre-baked)
#pragma unroll
    for (int i = 0; i < 6; ++i) {
      int e = (i * 512 + tid) * 8;
      int n = e >> 6, k = e & 63;
      gload16(wt + (size_t)n * EMBD + ks * 64 + k, &wts[e]);
    }
    __syncthreads();

#pragma unroll
    for (int kk = 0; kk < 2; ++kk) {
      bf16x8 a[2];
#pragma unroll
      for (int mf = 0; mf < 2; ++mf)
        a[mf] = *(const bf16x8*)&xs[(wm * 32 + mf * 16 + l15) * 72 + kk * 32 + lh * 8];
#pragma unroll
      for (int f = 0; f < 6; ++f) {
        int col = nm[f] + l15;
        int klin = (kk * 32 + lh * 8) ^ ((col & 7) << 3);
        bf16x8 b = *(const bf16x8*)&wts[col * 64 + klin];
#pragma unroll
        for (int mf = 0; mf < 2; ++mf)
          acc[mf][f] =
              __builtin_amdgcn_mfma_f32_16x16x32_bf16(a[mf], b, acc[mf][f], 0, 0, 0);
      }
    }
  }

  __syncthreads();
  bf16* vstage = wts;  // reuse (needs 128*72 = 9216 elems <= 24576)

#pragma unroll
  for (int fp = 0; fp < 3; ++fp) {
    const int c0A = nm[2 * fp], c0B = nm[2 * fp + 1];
    const int colA = c0A + l15, colB = c0B + l15;
    const bool rope = (c0A < 256);
    float biasA = (colA < 128) ? bq[colA] : ((colA < 256) ? bk[colA - 128] : bv[colA - 256]);
    float biasB = (colB < 128) ? bq[colB] : ((colB < 256) ? bk[colB - 128] : bv[colB - 256]);
    float invf = 0.f;
    if (rope) invf = exp2f((float)(colA & 63) * -0.20762050593046014f);  // -log2(1e4)/64
#pragma unroll
    for (int mf = 0; mf < 2; ++mf) {
#pragma unroll
      for (int r = 0; r < 4; ++r) {
        int grow = row0 + wm * 32 + mf * 16 + lh * 4 + r;
        int s = grow & (S_LEN - 1);
        int bb = grow >> 11;
        float xa = acc[mf][2 * fp][r] + biasA;
        float xb = acc[mf][2 * fp + 1][r] + biasB;
        float oa = xa, ob = xb;
        if (rope) {
          float sn, cs;
          sincosf((float)s * invf, &sn, &cs);
          oa = xa * cs - xb * sn;
          ob = xa * sn + xb * cs;
        }
        if (colA < 128) {
          Qw[(size_t)(bb * S_LEN + s) * HD + colA] = (bf16)oa;
        } else if (colA < 256) {
          int cc = colA - 128;
          Kw[(size_t)(bb * S_LEN + s) * HD + (cc ^ ((s & 7) << 3))] = (bf16)oa;
        } else {
          vstage[(colA - 256) * 72 + (grow - row0)] = (bf16)oa;
        }
        if (colB < 128) {
          Qw[(size_t)(bb * S_LEN + s) * HD + colB] = (bf16)ob;
        } else if (colB < 256) {
          int cc = colB - 128;
          Kw[(size_t)(bb * S_LEN + s) * HD + (cc ^ ((s & 7) << 3))] = (bf16)ob;
        } else {
          vstage[(colB - 256) * 72 + (grow - row0)] = (bf16)ob;
        }
      }
    }
  }

  __syncthreads();
  {  // cooperative transposed V store (16B chunks, swizzled token slot)
    int bb = row0 >> 11;
    int s0 = row0 & (S_LEN - 1);
#pragma unroll
    for (int i = 0; i < 2; ++i) {
      int c = i * 512 + tid;  // 0..1023: dv = c>>3, chunk kq = c&7
      int dv = c >> 3, kq = c & 7;
      uint4 v = *(const uint4*)&vstage[dv * 72 + kq * 8];
      int slot = (kq * 8) ^ ((dv & 7) << 3);
      *(uint4*)&Vtw[((size_t)(bb * HD + dv) << 11) + s0 + slot] = v;
    }
  }
}

// ---------------------------------------------------------------------------
// K2: causal flash attention. 1 block = (batch, q-tile of 64), 4 waves x 16 rows.
// ---------------------------------------------------------------------------
__global__ __launch_bounds__(256) void k_attn(
    const bf16* __restrict__ Qw, const bf16* __restrict__ Kw,
    const bf16* __restrict__ Vtw, float* __restrict__ out) {
  __shared__ __align__(16) bf16 ksld[64 * 128];
  __shared__ __align__(16) bf16 vsld[128 * 64];
  __shared__ __align__(16) bf16 pld[4 * 16 * 72];

  const int tid = threadIdx.x;
  const int lane = tid & 63;
  const int wave = tid >> 6;
  const int l15 = lane & 15;
  const int lh = lane >> 4;

  const int bid = blockIdx.x;
  const int batch = bid & 7;
  const int qt = 31 - (bid >> 3);  // longest blocks start first
  const int qbase = qt * 64;

  bf16x8 qa[4];
  {
    const bf16* qptr = Qw + (size_t)(batch * S_LEN + qbase + wave * 16 + l15) * HD;
#pragma unroll
    for (int kk = 0; kk < 4; ++kk) qa[kk] = *(const bf16x8*)(qptr + kk * 32 + lh * 8);
  }

  f32x4 o[8];
#pragma unroll
  for (int i = 0; i < 8; ++i) o[i] = {};
  float m[4], lsum[4];
#pragma unroll
  for (int r = 0; r < 4; ++r) { m[r] = -__builtin_inff(); lsum[r] = 0.f; }

  const float scale = 0.08838834764831845f;  // 1/sqrt(128)

  for (int t = 0; t <= qt; ++t) {
    const int kv0 = t * 64;
    __syncthreads();
    {
      const bf16* kbase = Kw + (size_t)(batch * S_LEN + kv0) * HD;
#pragma unroll
      for (int i = 0; i < 4; ++i) {
        int c = i * 256 + tid;
        gload16(kbase + c * 8, &ksld[c * 8]);  // fully linear 16 KB copy
      }
      const bf16* vbase = Vtw + ((size_t)(batch * HD) << 11) + kv0;
#pragma unroll
      for (int i = 0; i < 4; ++i) {
        int c = i * 256 + tid;
        int dv = c >> 3, kq = (c & 7) * 8;
        gload16(vbase + ((size_t)dv << 11) + kq, &vsld[c * 8]);
      }
    }
    __syncthreads();

    f32x4 sc[4];
#pragma unroll
    for (int nf = 0; nf < 4; ++nf) sc[nf] = {};
#pragma unroll
    for (int kk = 0; kk < 4; ++kk) {
#pragma unroll
      for (int nf = 0; nf < 4; ++nf) {
        int row = nf * 16 + l15;
        int dlin = (kk * 32 + lh * 8) ^ ((row & 7) << 3);
        bf16x8 kb = *(const bf16x8*)&ksld[row * 128 + dlin];
        sc[nf] = __builtin_amdgcn_mfma_f32_16x16x32_bf16(qa[kk], kb, sc[nf], 0, 0, 0);
      }
    }

    const bool diag = (t == qt);
    const int qg0 = qbase + wave * 16 + lh * 4;
#pragma unroll
    for (int nf = 0; nf < 4; ++nf) {
      int kvg = kv0 + nf * 16 + l15;
#pragma unroll
      for (int r = 0; r < 4; ++r) {
        float v = sc[nf][r] * scale;
        if (diag && kvg > qg0 + r) v = -__builtin_inff();
        sc[nf][r] = v;
      }
    }

    float mnew[4], alpha[4], rs[4];
#pragma unroll
    for (int r = 0; r < 4; ++r) {
      float v = fmaxf(fmaxf(sc[0][r], sc[1][r]), fmaxf(sc[2][r], sc[3][r]));
#pragma unroll
      for (int sh = 1; sh < 16; sh <<= 1) v = fmaxf(v, __shfl_xor(v, sh));
      mnew[r] = fmaxf(m[r], v);
      alpha[r] = __expf(m[r] - mnew[r]);
      m[r] = mnew[r];
      rs[r] = 0.f;
    }

    bf16* pw = &pld[wave * 16 * 72];
#pragma unroll
    for (int nf = 0; nf < 4; ++nf)
#pragma unroll
      for (int r = 0; r < 4; ++r) {
        float p = __expf(sc[nf][r] - mnew[r]);
        bf16 pb = (bf16)p;
        pw[(lh * 4 + r) * 72 + nf * 16 + l15] = pb;
        rs[r] += (float)pb;  // l-sum from the rounded P (numerator==denominator)
      }
#pragma unroll
    for (int r = 0; r < 4; ++r) {
      float v = rs[r];
#pragma unroll
      for (int sh = 1; sh < 16; sh <<= 1) v += __shfl_xor(v, sh);
      lsum[r] = lsum[r] * alpha[r] + v;
    }
#pragma unroll
    for (int i = 0; i < 8; ++i)
#pragma unroll
      for (int r = 0; r < 4; ++r) o[i][r] *= alpha[r];

#pragma unroll
    for (int kkv = 0; kkv < 2; ++kkv) {
      bf16x8 pa = *(const bf16x8*)&pw[l15 * 72 + kkv * 32 + lh * 8];
#pragma unroll
      for (int df = 0; df < 8; ++df) {
        int dv = df * 16 + l15;
        int klin = (kkv * 32 + lh * 8) ^ ((dv & 7) << 3);
        bf16x8 vb = *(const bf16x8*)&vsld[dv * 64 + klin];
        o[df] = __builtin_amdgcn_mfma_f32_16x16x32_bf16(pa, vb, o[df], 0, 0, 0);
      }
    }
  }

#pragma unroll
  for (int r = 0; r < 4; ++r) {
    int qg = qbase + wave * 16 + lh * 4 + r;
    float inv = 1.0f / lsum[r];
    float* op = out + (size_t)(batch * S_LEN + qg) * HD;
#pragma unroll
    for (int df = 0; df < 8; ++df) op[df * 16 + l15] = o[df][r] * inv;
  }
}

extern "C" void kernel_launch(void* const* d_in, const int* in_sizes, int n_in,
                              void* d_out, int out_size, void* d_ws, size_t ws_size,
                              hipStream_t stream) {
  const float* x = (const float*)d_in[0];
  const float* Wq = (const float*)d_in[1];
  const float* bq = (const float*)d_in[2];
  const float* Wk = (const float*)d_in[3];
  const float* bk = (const float*)d_in[4];
  const float* Wv = (const float*)d_in[5];
  const float* bv = (const float*)d_in[6];
  float* out = (float*)d_out;

  char* ws = (char*)d_ws;
  bf16* wt  = (bf16*)(ws);                       // 1.5 MB  (Wt, swizzled)
  bf16* Qw  = (bf16*)(ws + (size_t)(2u << 20));  // 4 MB
  bf16* Kw  = (bf16*)(ws + (size_t)(6u << 20));  // 4 MB
  bf16* Vtw = (bf16*)(ws + (size_t)(10u << 20)); // 4 MB

  hipLaunchKernelGGL(k_prep, dim3(1536), dim3(512), 0, stream, Wq, Wk, Wv, wt);
  hipLaunchKernelGGL(k_qkv, dim3(256), dim3(512), 0, stream, x, wt, bq, bk, bv,
                     Qw, Kw, Vtw);
  hipLaunchKernelGGL(k_attn, dim3(256), dim3(256), 0, stream, Qw, Kw, Vtw, out);
}

// Round 2
// 142.304 us; speedup vs baseline: 1.1578x; 1.1578x over previous
//
#include <hip/hip_runtime.h>

typedef __bf16 bf16;
typedef __bf16 bf16x8 __attribute__((ext_vector_type(8)));
typedef float f32x4 __attribute__((ext_vector_type(4)));

#define S_LEN 2048
#define EMBD 2048
#define HD 128
#define NBATCH 8

// frag->column map: pairs (2f,2f+1) are RoPE pairs (col, col+64) when col<256.
// cols 0-127 = Q, 128-255 = K, 256-383 = V.
__device__ __constant__ int c_nmap[4][6] = {
    {0, 64, 16, 80, 32, 96},
    {48, 112, 128, 192, 144, 208},
    {160, 224, 176, 240, 256, 272},
    {288, 304, 320, 336, 352, 368},
};

__device__ inline void gload16(const void* g, void* l) {
  __builtin_amdgcn_global_load_lds(
      (const __attribute__((address_space(1))) unsigned int*)g,
      (__attribute__((address_space(3))) unsigned int*)l, 16, 0, 0);
}

// ---------------------------------------------------------------------------
// K0: Wt[mat][n][k] = bf16( W[ (k&~63) | ((k&63) ^ ((n&7)<<3)) ][n] )
// (transpose + bf16 + bake the LDS XOR-swizzle into global layout)
// ---------------------------------------------------------------------------
__global__ void k_prep(const float* __restrict__ Wq, const float* __restrict__ Wk,
                       const float* __restrict__ Wv, bf16* __restrict__ wt) {
  int idx = blockIdx.x * blockDim.x + threadIdx.x;  // 3*128*2048 threads exact
  int k = idx & 2047;
  int n = (idx >> 11) & 127;
  int mat = idx >> 18;
  int ksrc = (k & ~63) | ((k & 63) ^ ((n & 7) << 3));
  const float* W = (mat == 0) ? Wq : ((mat == 1) ? Wk : Wv);
  wt[idx] = (bf16)W[(size_t)ksrc * HD + n];
}

// ---------------------------------------------------------------------------
// K1: fused QKV GEMM + bias + RoPE. BM=64, BN=384, BK=64, 8 waves (2m x 4n).
// Double-buffered pipeline: issue next-tile loads, compute current, one
// barrier per K-step (T3-minimum structure).
// ---------------------------------------------------------------------------
__global__ __launch_bounds__(512) void k_qkv(
    const float* __restrict__ x, const bf16* __restrict__ wt,
    const float* __restrict__ bq, const float* __restrict__ bk,
    const float* __restrict__ bv, bf16* __restrict__ Qw, bf16* __restrict__ Kw,
    bf16* __restrict__ Vtw) {
  __shared__ __align__(16) bf16 xs[2][64 * 72];    // padded rows: conflict-free
  __shared__ __align__(16) bf16 wts[2][384 * 64];  // linear, swizzle pre-baked

  const int tid = threadIdx.x;
  const int lane = tid & 63;
  const int wave = tid >> 6;
  const int wm = wave >> 2;  // 0..1
  const int wn = wave & 3;   // 0..3
  const int l15 = lane & 15;
  const int lh = lane >> 4;  // 0..3
  const int row0 = blockIdx.x * 64;

  int nm[6];
#pragma unroll
  for (int f = 0; f < 6; ++f) nm[f] = c_nmap[wn][f];

  f32x4 acc[2][6];
#pragma unroll
  for (int mf = 0; mf < 2; ++mf)
#pragma unroll
    for (int f = 0; f < 6; ++f) acc[mf][f] = {};

  // per-thread staging geometry (constant across iterations)
  const int xe = tid * 4;              // x element within 64x64 tile (2 chunks)
  const int xr0 = xe >> 6, xk0 = xe & 63;
  const int xe1 = (512 + tid) * 4;
  const int xr1 = xe1 >> 6, xk1 = xe1 & 63;

  auto stage_issue = [&](int ks, int buf, float4* xr) {
    // x -> regs (HBM; issue first for max lead time)
    xr[0] = *(const float4*)(x + (size_t)(row0 + xr0) * EMBD + ks * 64 + xk0);
    xr[1] = *(const float4*)(x + (size_t)(row0 + xr1) * EMBD + ks * 64 + xk1);
    // wt -> LDS direct (L2/L3-resident)
#pragma unroll
    for (int i = 0; i < 6; ++i) {
      int e = (i * 512 + tid) * 8;
      int n = e >> 6, k = e & 63;
      gload16(wt + (size_t)n * EMBD + ks * 64 + k, &wts[buf][e]);
    }
  };
  auto xwrite = [&](int buf, const float4* xr) {
    union { bf16 h[4]; uint2 u; } p;
    p.h[0] = (bf16)xr[0].x; p.h[1] = (bf16)xr[0].y;
    p.h[2] = (bf16)xr[0].z; p.h[3] = (bf16)xr[0].w;
    *(uint2*)&xs[buf][xr0 * 72 + xk0] = p.u;
    p.h[0] = (bf16)xr[1].x; p.h[1] = (bf16)xr[1].y;
    p.h[2] = (bf16)xr[1].z; p.h[3] = (bf16)xr[1].w;
    *(uint2*)&xs[buf][xr1 * 72 + xk1] = p.u;
  };

  {
    float4 xr[2];
    stage_issue(0, 0, xr);
    xwrite(0, xr);
  }
  __syncthreads();

  for (int ks = 0; ks < EMBD / 64; ++ks) {
    const int c = ks & 1, pbuf = c ^ 1;
    float4 xr[2];
    if (ks < EMBD / 64 - 1) stage_issue(ks + 1, pbuf, xr);

#pragma unroll
    for (int kk = 0; kk < 2; ++kk) {
      bf16x8 a[2];
#pragma unroll
      for (int mf = 0; mf < 2; ++mf)
        a[mf] = *(const bf16x8*)&xs[c][(wm * 32 + mf * 16 + l15) * 72 + kk * 32 + lh * 8];
#pragma unroll
      for (int f = 0; f < 6; ++f) {
        int col = nm[f] + l15;
        int klin = (kk * 32 + lh * 8) ^ ((col & 7) << 3);
        bf16x8 b = *(const bf16x8*)&wts[c][col * 64 + klin];
#pragma unroll
        for (int mf = 0; mf < 2; ++mf)
          acc[mf][f] =
              __builtin_amdgcn_mfma_f32_16x16x32_bf16(a[mf], b, acc[mf][f], 0, 0, 0);
      }
    }

    if (ks < EMBD / 64 - 1) xwrite(pbuf, xr);
    __syncthreads();
  }

  bf16* vstage = wts[0];  // reuse (needs 128*72 = 9216 elems)

#pragma unroll
  for (int fp = 0; fp < 3; ++fp) {
    const int c0A = nm[2 * fp], c0B = nm[2 * fp + 1];
    const int colA = c0A + l15, colB = c0B + l15;
    const bool rope = (c0A < 256);
    float biasA = (colA < 128) ? bq[colA] : ((colA < 256) ? bk[colA - 128] : bv[colA - 256]);
    float biasB = (colB < 128) ? bq[colB] : ((colB < 256) ? bk[colB - 128] : bv[colB - 256]);
    float invf = 0.f;
    if (rope) invf = exp2f((float)(colA & 63) * -0.20762050593046014f);  // -log2(1e4)/64
#pragma unroll
    for (int mf = 0; mf < 2; ++mf) {
#pragma unroll
      for (int r = 0; r < 4; ++r) {
        int grow = row0 + wm * 32 + mf * 16 + lh * 4 + r;
        int s = grow & (S_LEN - 1);
        int bb = grow >> 11;
        float xa = acc[mf][2 * fp][r] + biasA;
        float xb = acc[mf][2 * fp + 1][r] + biasB;
        float oa = xa, ob = xb;
        if (rope) {
          float sn, cs;
          sincosf((float)s * invf, &sn, &cs);
          oa = xa * cs - xb * sn;
          ob = xa * sn + xb * cs;
        }
        if (colA < 128) {
          Qw[(size_t)(bb * S_LEN + s) * HD + colA] = (bf16)oa;
        } else if (colA < 256) {
          int cc = colA - 128;
          Kw[(size_t)(bb * S_LEN + s) * HD + (cc ^ ((s & 7) << 3))] = (bf16)oa;
        } else {
          vstage[(colA - 256) * 72 + (grow - row0)] = (bf16)oa;
        }
        if (colB < 128) {
          Qw[(size_t)(bb * S_LEN + s) * HD + colB] = (bf16)ob;
        } else if (colB < 256) {
          int cc = colB - 128;
          Kw[(size_t)(bb * S_LEN + s) * HD + (cc ^ ((s & 7) << 3))] = (bf16)ob;
        } else {
          vstage[(colB - 256) * 72 + (grow - row0)] = (bf16)ob;
        }
      }
    }
  }

  __syncthreads();
  {  // cooperative transposed V store (16B chunks, swizzled token slot)
    int bb = row0 >> 11;
    int s0 = row0 & (S_LEN - 1);
#pragma unroll
    for (int i = 0; i < 2; ++i) {
      int c = i * 512 + tid;  // 0..1023: dv = c>>3, chunk kq = c&7
      int dv = c >> 3, kq = c & 7;
      uint4 v = *(const uint4*)&vstage[dv * 72 + kq * 8];
      int slot = (kq * 8) ^ ((dv & 7) << 3);
      *(uint4*)&Vtw[((size_t)(bb * HD + dv) << 11) + s0 + slot] = v;
    }
  }
}

// ---------------------------------------------------------------------------
// K2: causal flash attention. 1 block = (batch, q-tile of 64), 4 waves x 16
// rows. K/V double-buffered with one-tile lookahead.
// ---------------------------------------------------------------------------
__global__ __launch_bounds__(256) void k_attn(
    const bf16* __restrict__ Qw, const bf16* __restrict__ Kw,
    const bf16* __restrict__ Vtw, float* __restrict__ out) {
  __shared__ __align__(16) bf16 ksld[2][64 * 128];
  __shared__ __align__(16) bf16 vsld[2][128 * 64];
  __shared__ __align__(16) bf16 pld[4 * 16 * 72];

  const int tid = threadIdx.x;
  const int lane = tid & 63;
  const int wave = tid >> 6;
  const int l15 = lane & 15;
  const int lh = lane >> 4;

  const int bid = blockIdx.x;
  const int batch = bid & 7;
  const int qt = 31 - (bid >> 3);  // longest blocks start first
  const int qbase = qt * 64;

  const bf16* kbat = Kw + (size_t)(batch * S_LEN) * HD;
  const bf16* vbat = Vtw + ((size_t)(batch * HD) << 11);

  auto stageKV = [&](int t, int buf) {
    const bf16* kbase = kbat + (size_t)(t * 64) * HD;
#pragma unroll
    for (int i = 0; i < 4; ++i) {
      int c = i * 256 + tid;
      gload16(kbase + c * 8, &ksld[buf][c * 8]);  // fully linear 16 KB copy
    }
    const bf16* vbase = vbat + t * 64;
#pragma unroll
    for (int i = 0; i < 4; ++i) {
      int c = i * 256 + tid;
      int dv = c >> 3, kq = (c & 7) * 8;
      gload16(vbase + ((size_t)dv << 11) + kq, &vsld[buf][c * 8]);
    }
  };

  bf16x8 qa[4];
  {
    const bf16* qptr = Qw + (size_t)(batch * S_LEN + qbase + wave * 16 + l15) * HD;
#pragma unroll
    for (int kk = 0; kk < 4; ++kk) qa[kk] = *(const bf16x8*)(qptr + kk * 32 + lh * 8);
  }

  f32x4 o[8];
#pragma unroll
  for (int i = 0; i < 8; ++i) o[i] = {};
  float m[4], lsum[4];
#pragma unroll
  for (int r = 0; r < 4; ++r) { m[r] = -__builtin_inff(); lsum[r] = 0.f; }

  const float scale = 0.08838834764831845f;  // 1/sqrt(128)

  stageKV(0, 0);
  __syncthreads();

  for (int t = 0; t <= qt; ++t) {
    const int kv0 = t * 64;
    const int c = t & 1;
    if (t < qt) stageKV(t + 1, c ^ 1);

    f32x4 sc[4];
#pragma unroll
    for (int nf = 0; nf < 4; ++nf) sc[nf] = {};
#pragma unroll
    for (int kk = 0; kk < 4; ++kk) {
#pragma unroll
      for (int nf = 0; nf < 4; ++nf) {
        int row = nf * 16 + l15;
        int dlin = (kk * 32 + lh * 8) ^ ((row & 7) << 3);
        bf16x8 kb = *(const bf16x8*)&ksld[c][row * 128 + dlin];
        sc[nf] = __builtin_amdgcn_mfma_f32_16x16x32_bf16(qa[kk], kb, sc[nf], 0, 0, 0);
      }
    }

    const bool diag = (t == qt);
    const int qg0 = qbase + wave * 16 + lh * 4;
#pragma unroll
    for (int nf = 0; nf < 4; ++nf) {
      int kvg = kv0 + nf * 16 + l15;
#pragma unroll
      for (int r = 0; r < 4; ++r) {
        float v = sc[nf][r] * scale;
        if (diag && kvg > qg0 + r) v = -__builtin_inff();
        sc[nf][r] = v;
      }
    }

    float mnew[4], alpha[4], rs[4];
#pragma unroll
    for (int r = 0; r < 4; ++r) {
      float v = fmaxf(fmaxf(sc[0][r], sc[1][r]), fmaxf(sc[2][r], sc[3][r]));
#pragma unroll
      for (int sh = 1; sh < 16; sh <<= 1) v = fmaxf(v, __shfl_xor(v, sh));
      mnew[r] = fmaxf(m[r], v);
      alpha[r] = __expf(m[r] - mnew[r]);
      m[r] = mnew[r];
      rs[r] = 0.f;
    }

    bf16* pw = &pld[wave * 16 * 72];
#pragma unroll
    for (int nf = 0; nf < 4; ++nf)
#pragma unroll
      for (int r = 0; r < 4; ++r) {
        float p = __expf(sc[nf][r] - mnew[r]);
        bf16 pb = (bf16)p;
        pw[(lh * 4 + r) * 72 + nf * 16 + l15] = pb;
        rs[r] += (float)pb;  // l-sum from the rounded P (numerator==denominator)
      }
#pragma unroll
    for (int r = 0; r < 4; ++r) {
      float v = rs[r];
#pragma unroll
      for (int sh = 1; sh < 16; sh <<= 1) v += __shfl_xor(v, sh);
      lsum[r] = lsum[r] * alpha[r] + v;
    }
#pragma unroll
    for (int i = 0; i < 8; ++i)
#pragma unroll
      for (int r = 0; r < 4; ++r) o[i][r] *= alpha[r];

#pragma unroll
    for (int kkv = 0; kkv < 2; ++kkv) {
      bf16x8 pa = *(const bf16x8*)&pw[l15 * 72 + kkv * 32 + lh * 8];
#pragma unroll
      for (int df = 0; df < 8; ++df) {
        int dv = df * 16 + l15;
        int klin = (kkv * 32 + lh * 8) ^ ((dv & 7) << 3);
        bf16x8 vb = *(const bf16x8*)&vsld[c][dv * 64 + klin];
        o[df] = __builtin_amdgcn_mfma_f32_16x16x32_bf16(pa, vb, o[df], 0, 0, 0);
      }
    }
    __syncthreads();
  }

#pragma unroll
  for (int r = 0; r < 4; ++r) {
    int qg = qbase + wave * 16 + lh * 4 + r;
    float inv = 1.0f / lsum[r];
    float* op = out + (size_t)(batch * S_LEN + qg) * HD;
#pragma unroll
    for (int df = 0; df < 8; ++df) op[df * 16 + l15] = o[df][r] * inv;
  }
}

extern "C" void kernel_launch(void* const* d_in, const int* in_sizes, int n_in,
                              void* d_out, int out_size, void* d_ws, size_t ws_size,
                              hipStream_t stream) {
  const float* x = (const float*)d_in[0];
  const float* Wq = (const float*)d_in[1];
  const float* bq = (const float*)d_in[2];
  const float* Wk = (const float*)d_in[3];
  const float* bk = (const float*)d_in[4];
  const float* Wv = (const float*)d_in[5];
  const float* bv = (const float*)d_in[6];
  float* out = (float*)d_out;

  char* ws = (char*)d_ws;
  bf16* wt  = (bf16*)(ws);                       // 1.5 MB  (Wt, swizzled)
  bf16* Qw  = (bf16*)(ws + (size_t)(2u << 20));  // 4 MB
  bf16* Kw  = (bf16*)(ws + (size_t)(6u << 20));  // 4 MB
  bf16* Vtw = (bf16*)(ws + (size_t)(10u << 20)); // 4 MB

  hipLaunchKernelGGL(k_prep, dim3(1536), dim3(512), 0, stream, Wq, Wk, Wv, wt);
  hipLaunchKernelGGL(k_qkv, dim3(256), dim3(512), 0, stream, x, wt, bq, bk, bv,
                     Qw, Kw, Vtw);
  hipLaunchKernelGGL(k_attn, dim3(256), dim3(256), 0, stream, Qw, Kw, Vtw, out);
}

// Round 3
// 104.346 us; speedup vs baseline: 1.5790x; 1.3638x over previous
//
#include <hip/hip_runtime.h>

typedef __bf16 bf16;
typedef __bf16 bf16x8 __attribute__((ext_vector_type(8)));
typedef float f32x4 __attribute__((ext_vector_type(4)));

#define S_LEN 2048
#define EMBD 2048
#define HD 128

__device__ inline void gload16(const void* g, void* l) {
  __builtin_amdgcn_global_load_lds(
      (const __attribute__((address_space(1))) unsigned int*)g,
      (__attribute__((address_space(3))) unsigned int*)l, 16, 0, 0);
}

// ---------------------------------------------------------------------------
// K0: Wt[mat][n][k] = bf16( W[ (k&~63) | ((k&63) ^ ((n&7)<<3)) ][n] )
// ---------------------------------------------------------------------------
__global__ void k_prep(const float* __restrict__ Wq, const float* __restrict__ Wk,
                       const float* __restrict__ Wv, bf16* __restrict__ wt) {
  int idx = blockIdx.x * blockDim.x + threadIdx.x;  // 3*128*2048 threads exact
  int k = idx & 2047;
  int n = (idx >> 11) & 127;
  int mat = idx >> 18;
  int ksrc = (k & ~63) | ((k & 63) ^ ((n & 7) << 3));
  const float* W = (mat == 0) ? Wq : ((mat == 1) ? Wk : Wv);
  wt[idx] = (bf16)W[(size_t)ksrc * HD + n];
}

// ---------------------------------------------------------------------------
// K1: fused QKV GEMM + bias + RoPE. BM=64, BN=192 (by0: Q + V[0:64],
// by1: K + V[64:128]), BK=64, 8 waves (2m x 4n), grid 512 -> 2 blocks/CU.
// ---------------------------------------------------------------------------
__global__ __launch_bounds__(512) void k_qkv(
    const float* __restrict__ x, const bf16* __restrict__ wt,
    const float* __restrict__ bq, const float* __restrict__ bk,
    const float* __restrict__ bv, bf16* __restrict__ Qw, bf16* __restrict__ Kw,
    bf16* __restrict__ Vtw) {
  __shared__ __align__(16) bf16 xs[2][64 * 72];    // 18.4 KB
  __shared__ __align__(16) bf16 wts[2][192 * 64];  // 48 KB

  const int tid = threadIdx.x;
  const int lane = tid & 63;
  const int wave = tid >> 6;
  const int wm = wave >> 2;  // 0..1
  const int wn = wave & 3;   // 0..3
  const int l15 = lane & 15;
  const int lh = lane >> 4;  // 0..3
  const int bx = blockIdx.x & 255;
  const int by = blockIdx.x >> 8;  // 0: Q+Vlo, 1: K+Vhi
  const int row0 = bx * 64;

  f32x4 acc[2][3];
#pragma unroll
  for (int mf = 0; mf < 2; ++mf)
#pragma unroll
    for (int f = 0; f < 3; ++f) acc[mf][f] = {};

  // staging geometry (loop-invariant)
  const int xe0 = tid * 4;
  const int xr0 = xe0 >> 6, xk0 = xe0 & 63;
  const int xe1 = (512 + tid) * 4;
  const int xr1 = xe1 >> 6, xk1 = xe1 & 63;
  const float* xp0 = x + (size_t)(row0 + xr0) * EMBD + xk0;
  const float* xp1 = x + (size_t)(row0 + xr1) * EMBD + xk1;

  const bf16* wp[3];
  int we[3];
#pragma unroll
  for (int i = 0; i < 3; ++i) {
    int e = (i * 512 + tid) * 8;
    int np = e >> 6, k = e & 63;  // lds row 0..191
    int ng = (np < 128) ? by * 128 + np : 256 + by * 64 + (np - 128);
    wp[i] = wt + (size_t)ng * EMBD + k;
    we[i] = e;
  }

  auto stage_issue = [&](int ks, int buf, float4* xr) {
    xr[0] = *(const float4*)(xp0 + ks * 64);
    xr[1] = *(const float4*)(xp1 + ks * 64);
#pragma unroll
    for (int i = 0; i < 3; ++i) gload16(wp[i] + ks * 64, &wts[buf][we[i]]);
  };
  auto xwrite = [&](int buf, const float4* xr) {
    union { bf16 h[4]; uint2 u; } p;
    p.h[0] = (bf16)xr[0].x; p.h[1] = (bf16)xr[0].y;
    p.h[2] = (bf16)xr[0].z; p.h[3] = (bf16)xr[0].w;
    *(uint2*)&xs[buf][xr0 * 72 + xk0] = p.u;
    p.h[0] = (bf16)xr[1].x; p.h[1] = (bf16)xr[1].y;
    p.h[2] = (bf16)xr[1].z; p.h[3] = (bf16)xr[1].w;
    *(uint2*)&xs[buf][xr1 * 72 + xk1] = p.u;
  };

  {
    float4 xr[2];
    stage_issue(0, 0, xr);
    xwrite(0, xr);
  }
  __syncthreads();

  for (int ks = 0; ks < EMBD / 64; ++ks) {
    const int c = ks & 1, pbuf = c ^ 1;
    float4 xr[2];
    if (ks < EMBD / 64 - 1) stage_issue(ks + 1, pbuf, xr);

#pragma unroll
    for (int kk = 0; kk < 2; ++kk) {
      bf16x8 a[2];
#pragma unroll
      for (int mf = 0; mf < 2; ++mf)
        a[mf] = *(const bf16x8*)&xs[c][(wm * 32 + mf * 16 + l15) * 72 + kk * 32 + lh * 8];
      const int klin = (kk * 32 + lh * 8) ^ ((l15 & 7) << 3);
#pragma unroll
      for (int f = 0; f < 3; ++f) {
        bf16x8 b = *(const bf16x8*)&wts[c][(f * 64 + wn * 16 + l15) * 64 + klin];
#pragma unroll
        for (int mf = 0; mf < 2; ++mf)
          acc[mf][f] =
              __builtin_amdgcn_mfma_f32_16x16x32_bf16(a[mf], b, acc[mf][f], 0, 0, 0);
      }
    }

    if (ks < EMBD / 64 - 1) xwrite(pbuf, xr);
    __syncthreads();
  }

  bf16* vstage = wts[0];  // 64*72 elems

  // f0/f1: RoPE pair (Q for by0, K for by1)
  {
    const int colA = by * 128 + wn * 16 + l15;
    const int colB = colA + 64;
    float biasA = (colA < 128) ? bq[colA] : bk[colA - 128];
    float biasB = (colB < 128) ? bq[colB] : bk[colB - 128];
    float invf = exp2f((float)(colA & 63) * -0.20762050593046014f);  // -log2(1e4)/64
#pragma unroll
    for (int mf = 0; mf < 2; ++mf) {
#pragma unroll
      for (int r = 0; r < 4; ++r) {
        int grow = row0 + wm * 32 + mf * 16 + lh * 4 + r;
        int s = grow & (S_LEN - 1);
        int bb = grow >> 11;
        float xa = acc[mf][0][r] + biasA;
        float xb = acc[mf][1][r] + biasB;
        float sn, cs;
        sincosf((float)s * invf, &sn, &cs);
        float oa = xa * cs - xb * sn;
        float ob = xa * sn + xb * cs;
        if (by == 0) {
          Qw[(size_t)(bb * S_LEN + s) * HD + colA] = (bf16)oa;
          Qw[(size_t)(bb * S_LEN + s) * HD + colB] = (bf16)ob;
        } else {
          int ccA = colA - 128, ccB = colB - 128;
          int sw = (s & 7) << 3;
          Kw[(size_t)(bb * S_LEN + s) * HD + (ccA ^ sw)] = (bf16)oa;
          Kw[(size_t)(bb * S_LEN + s) * HD + (ccB ^ sw)] = (bf16)ob;
        }
      }
    }
  }
  // f2: V (no rope) -> LDS transpose stage
  {
    const int dvl = wn * 16 + l15;  // 0..63 local
    float biasV = bv[by * 64 + dvl];
#pragma unroll
    for (int mf = 0; mf < 2; ++mf)
#pragma unroll
      for (int r = 0; r < 4; ++r) {
        int mrow = wm * 32 + mf * 16 + lh * 4 + r;
        vstage[dvl * 72 + mrow] = (bf16)(acc[mf][2][r] + biasV);
      }
  }
  __syncthreads();
  {  // transposed V store: 512 chunks of 16B
    int dvl = tid >> 3, kq = tid & 7;
    uint4 v = *(const uint4*)&vstage[dvl * 72 + kq * 8];
    int dv = by * 64 + dvl;
    int slot = (kq * 8) ^ ((dvl & 7) << 3);
    int bb = row0 >> 11;
    int s0 = row0 & (S_LEN - 1);
    *(uint4*)&Vtw[((size_t)(bb * HD + dv) << 11) + s0 + slot] = v;
  }
}

// ---------------------------------------------------------------------------
// K2: causal flash attention. 512 thr = 2 groups x 4 waves; groups split the
// KV range (even/odd tiles) and merge (m,l,o) via LDS at the end.
// ---------------------------------------------------------------------------
__global__ __launch_bounds__(512) void k_attn(
    const bf16* __restrict__ Qw, const bf16* __restrict__ Kw,
    const bf16* __restrict__ Vtw, float* __restrict__ out) {
  __shared__ __align__(16) char arena[131072];       // 128 KB: K/V dbuf x 2 grp
  __shared__ __align__(16) bf16 pld[8 * 16 * 72];    // 18.4 KB
  __shared__ float mls[64], lls[64];

  bf16(*kls)[64 * 128] = (bf16(*)[64 * 128])arena;             // [grp*2+buf]
  bf16(*vls)[128 * 64] = (bf16(*)[128 * 64])(arena + 65536);   // [grp*2+buf]
  float* oml = (float*)arena;  // merge area: 64 x 128 f32 (aliases kls[0..1])

  const int tid = threadIdx.x;
  const int lane = tid & 63;
  const int wave = tid >> 6;
  const int grp = wave >> 2;
  const int w4 = wave & 3;
  const int l15 = lane & 15;
  const int lh = lane >> 4;
  const int t256 = tid & 255;

  const int bid = blockIdx.x;
  const int batch = bid & 7;  // batch == XCD (round-robin) -> KV L2 locality
  const int qt = 31 - (bid >> 3);
  const int qbase = qt * 64;
  const int nt = qt + 1;
  const int mysteps = (nt - grp + 1) >> 1;  // grp0: ceil(nt/2), grp1: floor
  const int maxst = (nt + 1) >> 1;

  const bf16* kbat = Kw + (size_t)(batch * S_LEN) * HD;
  const bf16* vbat = Vtw + ((size_t)(batch * HD) << 11);

  auto stage = [&](int t, int buf) {
    bf16* kdst = kls[grp * 2 + buf];
    bf16* vdst = vls[grp * 2 + buf];
    const bf16* kbase = kbat + (size_t)(t * 64) * HD;
#pragma unroll
    for (int i = 0; i < 4; ++i) {
      int c = i * 256 + t256;
      gload16(kbase + c * 8, kdst + c * 8);
    }
    const bf16* vbase = vbat + t * 64;
#pragma unroll
    for (int i = 0; i < 4; ++i) {
      int c = i * 256 + t256;
      int dv = c >> 3, kq = (c & 7) * 8;
      gload16(vbase + ((size_t)dv << 11) + kq, vdst + c * 8);
    }
  };

  bf16x8 qa[4];
  {
    const bf16* qptr = Qw + (size_t)(batch * S_LEN + qbase + w4 * 16 + l15) * HD;
#pragma unroll
    for (int kk = 0; kk < 4; ++kk) qa[kk] = *(const bf16x8*)(qptr + kk * 32 + lh * 8);
  }

  f32x4 o[8];
#pragma unroll
  for (int i = 0; i < 8; ++i) o[i] = {};
  float m[4], lsum[4];
#pragma unroll
  for (int r = 0; r < 4; ++r) { m[r] = -__builtin_inff(); lsum[r] = 0.f; }

  const float scale = 0.08838834764831845f;  // 1/sqrt(128)

  if (mysteps > 0) stage(grp, 0);
  __syncthreads();

  for (int i = 0; i < maxst; ++i) {
    if (i + 1 < mysteps) stage(2 * (i + 1) + grp, (i + 1) & 1);
    if (i < mysteps) {
      const int t = 2 * i + grp;
      const int buf = grp * 2 + (i & 1);
      const int kv0 = t * 64;

      f32x4 sc[4];
#pragma unroll
      for (int nf = 0; nf < 4; ++nf) sc[nf] = {};
      __builtin_amdgcn_s_setprio(1);
#pragma unroll
      for (int kk = 0; kk < 4; ++kk) {
#pragma unroll
        for (int nf = 0; nf < 4; ++nf) {
          int row = nf * 16 + l15;
          int dlin = (kk * 32 + lh * 8) ^ ((row & 7) << 3);
          bf16x8 kb = *(const bf16x8*)&kls[buf][row * 128 + dlin];
          sc[nf] = __builtin_amdgcn_mfma_f32_16x16x32_bf16(qa[kk], kb, sc[nf], 0, 0, 0);
        }
      }
      __builtin_amdgcn_s_setprio(0);

      const bool diag = (t == qt);
      const int qg0 = qbase + w4 * 16 + lh * 4;
#pragma unroll
      for (int nf = 0; nf < 4; ++nf) {
        int kvg = kv0 + nf * 16 + l15;
#pragma unroll
        for (int r = 0; r < 4; ++r) {
          float v = sc[nf][r] * scale;
          if (diag && kvg > qg0 + r) v = -__builtin_inff();
          sc[nf][r] = v;
        }
      }

      float mnew[4], alpha[4], rs[4];
#pragma unroll
      for (int r = 0; r < 4; ++r) {
        float v = fmaxf(fmaxf(sc[0][r], sc[1][r]), fmaxf(sc[2][r], sc[3][r]));
#pragma unroll
        for (int sh = 1; sh < 16; sh <<= 1) v = fmaxf(v, __shfl_xor(v, sh));
        mnew[r] = fmaxf(m[r], v);
        alpha[r] = __expf(m[r] - mnew[r]);
        m[r] = mnew[r];
        rs[r] = 0.f;
      }

      bf16* pw = &pld[wave * 16 * 72];
#pragma unroll
      for (int nf = 0; nf < 4; ++nf)
#pragma unroll
        for (int r = 0; r < 4; ++r) {
          float p = __expf(sc[nf][r] - mnew[r]);
          bf16 pb = (bf16)p;
          pw[(lh * 4 + r) * 72 + nf * 16 + l15] = pb;
          rs[r] += (float)pb;
        }
#pragma unroll
      for (int r = 0; r < 4; ++r) {
        float v = rs[r];
#pragma unroll
        for (int sh = 1; sh < 16; sh <<= 1) v += __shfl_xor(v, sh);
        lsum[r] = lsum[r] * alpha[r] + v;
      }
#pragma unroll
      for (int i2 = 0; i2 < 8; ++i2)
#pragma unroll
        for (int r = 0; r < 4; ++r) o[i2][r] *= alpha[r];

      __builtin_amdgcn_s_setprio(1);
#pragma unroll
      for (int kkv = 0; kkv < 2; ++kkv) {
        bf16x8 pa = *(const bf16x8*)&pw[l15 * 72 + kkv * 32 + lh * 8];
#pragma unroll
        for (int df = 0; df < 8; ++df) {
          int dv = df * 16 + l15;
          int klin = (kkv * 32 + lh * 8) ^ ((dv & 7) << 3);
          bf16x8 vb = *(const bf16x8*)&vls[buf][dv * 64 + klin];
          o[df] = __builtin_amdgcn_mfma_f32_16x16x32_bf16(pa, vb, o[df], 0, 0, 0);
        }
      }
      __builtin_amdgcn_s_setprio(0);
    }
    __syncthreads();
  }

  // merge: group1 publishes (o, m, l); group0 combines and stores.
  if (grp == 1) {
#pragma unroll
    for (int df = 0; df < 8; ++df)
#pragma unroll
      for (int r = 0; r < 4; ++r)
        oml[(w4 * 16 + lh * 4 + r) * 128 + df * 16 + l15] = o[df][r];
    if (l15 == 0) {
#pragma unroll
      for (int r = 0; r < 4; ++r) {
        mls[w4 * 16 + lh * 4 + r] = m[r];
        lls[w4 * 16 + lh * 4 + r] = lsum[r];
      }
    }
  }
  __syncthreads();
  if (grp == 0) {
#pragma unroll
    for (int r = 0; r < 4; ++r) {
      int row = w4 * 16 + lh * 4 + r;
      float m1 = mls[row], l1 = lls[row];
      float mm = fmaxf(m[r], m1);
      float s0 = __expf(m[r] - mm);
      float s1 = __expf(m1 - mm);
      float inv = 1.0f / (lsum[r] * s0 + l1 * s1);
      float* op = out + (size_t)(batch * S_LEN + qbase + row) * HD;
#pragma unroll
      for (int df = 0; df < 8; ++df)
        op[df * 16 + l15] =
            (o[df][r] * s0 + oml[row * 128 + df * 16 + l15] * s1) * inv;
    }
  }
}

extern "C" void kernel_launch(void* const* d_in, const int* in_sizes, int n_in,
                              void* d_out, int out_size, void* d_ws, size_t ws_size,
                              hipStream_t stream) {
  const float* x = (const float*)d_in[0];
  const float* Wq = (const float*)d_in[1];
  const float* bq = (const float*)d_in[2];
  const float* Wk = (const float*)d_in[3];
  const float* bk = (const float*)d_in[4];
  const float* Wv = (const float*)d_in[5];
  const float* bv = (const float*)d_in[6];
  float* out = (float*)d_out;

  char* ws = (char*)d_ws;
  bf16* wt  = (bf16*)(ws);                       // 1.5 MB  (Wt, swizzled)
  bf16* Qw  = (bf16*)(ws + (size_t)(2u << 20));  // 4 MB
  bf16* Kw  = (bf16*)(ws + (size_t)(6u << 20));  // 4 MB
  bf16* Vtw = (bf16*)(ws + (size_t)(10u << 20)); // 4 MB

  hipLaunchKernelGGL(k_prep, dim3(1536), dim3(512), 0, stream, Wq, Wk, Wv, wt);
  hipLaunchKernelGGL(k_qkv, dim3(512), dim3(512), 0, stream, x, wt, bq, bk, bv,
                     Qw, Kw, Vtw);
  hipLaunchKernelGGL(k_attn, dim3(256), dim3(512), 0, stream, Qw, Kw, Vtw, out);
}